// Round 1
// baseline (277.259 us; speedup 1.0000x reference)
//
#include <hip/hip_runtime.h>
#include <hip/hip_bf16.h>
#include <cstdint>
#include <cstddef>

#define NB 2
#define NS 2048
#define ND 1024
#define NH 16
#define NDK 64

typedef __attribute__((ext_vector_type(4))) float f32x4;
typedef __attribute__((ext_vector_type(8))) short bf16x8;

#define MFMA_16x16x32_BF16(a,b,c) __builtin_amdgcn_mfma_f32_16x16x32_bf16((a),(b),(c),0,0,0)

__device__ __forceinline__ uint16_t f2bf(float f){
  uint32_t u = __float_as_uint(f);
  u += 0x7fffu + ((u >> 16) & 1u);   // round-to-nearest-even
  return (uint16_t)(u >> 16);
}

// ---------------- f32 -> bf16 convert (vectorized, 8 elem/thread/iter) ------
__global__ void cvt_f32_bf16(const float* __restrict__ in, uint16_t* __restrict__ out, int n8){
  int i0 = blockIdx.x * blockDim.x + threadIdx.x;
  int stride = gridDim.x * blockDim.x;
  for(int i = i0; i < n8; i += stride){
    const float4* p = (const float4*)(in) + (size_t)i * 2;
    float4 a = p[0], b = p[1];
    bf16x8 o;
    o[0]=(short)f2bf(a.x); o[1]=(short)f2bf(a.y); o[2]=(short)f2bf(a.z); o[3]=(short)f2bf(a.w);
    o[4]=(short)f2bf(b.x); o[5]=(short)f2bf(b.y); o[6]=(short)f2bf(b.z); o[7]=(short)f2bf(b.w);
    *((bf16x8*)(out) + i) = o;
  }
}

// ---------------- GEMM: C[m,n] = sum_k A[m,k]*W[n,k] + bias[n] --------------
// A [M,K] bf16 row-major, W [N,K] bf16 row-major (torch Linear W), 128x128 tile,
// BK=32, 4 waves each owning a 64x64 sub-tile (4x4 frags of 16x16x32 MFMA).
// blockIdx.z selects one of three (A,W,bias,C) sets (fused QKV projection).
template<bool OUTF32>
__global__ __launch_bounds__(256)
void gemm_bt(const uint16_t* __restrict__ A0, const uint16_t* __restrict__ A1, const uint16_t* __restrict__ A2,
             const uint16_t* __restrict__ W0, const uint16_t* __restrict__ W1, const uint16_t* __restrict__ W2,
             const float* __restrict__ b0, const float* __restrict__ b1, const float* __restrict__ b2,
             void* __restrict__ C0, void* __restrict__ C1, void* __restrict__ C2,
             int M, int N, int K)
{
  const int z = blockIdx.z;
  const uint16_t* A   = (z == 0) ? A0 : (z == 1) ? A1 : A2;
  const uint16_t* W   = (z == 0) ? W0 : (z == 1) ? W1 : W2;
  const float*   bias = (z == 0) ? b0 : (z == 1) ? b1 : b2;
  void*          Cout = (z == 0) ? C0 : (z == 1) ? C1 : C2;

  // +8 pad (row=40 elems=80B, multiple of 16B): frag ds_read_b128 is 2-way -> free
  __shared__ __align__(16) uint16_t Asm[128][40];
  __shared__ __align__(16) uint16_t Bsm[128][40];

  const int t = threadIdx.x;
  const int lane = t & 63, w = t >> 6;
  const int l15 = lane & 15, g = lane >> 4;
  const int bm = blockIdx.y * 128, bn = blockIdx.x * 128;
  const int wr = (w >> 1) * 64, wc = (w & 1) * 64;

  f32x4 acc[4][4] = {};

  const int sr = t >> 2, sc = (t & 3) * 8;   // staging: 4 threads/row, 8 elems each

  for(int k0 = 0; k0 < K; k0 += 32){
    #pragma unroll
    for(int i = 0; i < 2; ++i){
      int r = sr + i * 64;
      *(bf16x8*)&Asm[r][sc] = *(const bf16x8*)(A + (size_t)(bm + r) * K + k0 + sc);
      *(bf16x8*)&Bsm[r][sc] = *(const bf16x8*)(W + (size_t)(bn + r) * K + k0 + sc);
    }
    __syncthreads();
    bf16x8 af[4], bfr[4];
    #pragma unroll
    for(int m = 0; m < 4; ++m) af[m]  = *(const bf16x8*)&Asm[wr + m*16 + l15][g*8];
    #pragma unroll
    for(int n = 0; n < 4; ++n) bfr[n] = *(const bf16x8*)&Bsm[wc + n*16 + l15][g*8];
    #pragma unroll
    for(int m = 0; m < 4; ++m)
      #pragma unroll
      for(int n = 0; n < 4; ++n)
        acc[m][n] = MFMA_16x16x32_BF16(af[m], bfr[n], acc[m][n]);
    __syncthreads();
  }

  // Epilogue: C/D layout col = lane&15, row = (lane>>4)*4 + j  [m89-verified]
  #pragma unroll
  for(int m = 0; m < 4; ++m){
    const int row = bm + wr + m*16 + g*4;
    #pragma unroll
    for(int n = 0; n < 4; ++n){
      const int col = bn + wc + n*16 + l15;
      const float bv = bias[col];
      #pragma unroll
      for(int j = 0; j < 4; ++j){
        float v = acc[m][n][j] + bv;
        if (OUTF32) ((float*)Cout)[(size_t)(row + j) * N + col] = v;
        else        ((uint16_t*)Cout)[(size_t)(row + j) * N + col] = f2bf(v);
      }
    }
  }
}

// ---------------- Flash attention -------------------------------------------
// Grid (S/64, H, B), 256 threads = 4 waves. Wave w owns 16 q-rows.
// K tile [64 kv][64 dk] and transposed V tile [64 dk][64 kv] staged in LDS
// (row pad +8 -> 2-way bank aliasing = free). Online softmax in f32.
__global__ __launch_bounds__(256)
void attn_fwd(const uint16_t* __restrict__ Qp, const uint16_t* __restrict__ Kp,
              const uint16_t* __restrict__ Vp, const int* __restrict__ mask,
              uint16_t* __restrict__ Xo)
{
  __shared__ __align__(16) uint16_t Ksm[64][72];
  __shared__ __align__(16) uint16_t Vtsm[64][72];
  __shared__ __align__(16) uint16_t Psm[4][16][40];

  const int t = threadIdx.x, lane = t & 63, w = t >> 6;
  const int l15 = lane & 15, g = lane >> 4;
  const int b = blockIdx.z, h = blockIdx.y, q0 = blockIdx.x * 64;
  const int qbase = q0 + w * 16;

  // Q fragment: row = qbase + (lane&15), k = 32*c + (lane>>4)*8 .. +7
  bf16x8 qf[2];
  {
    const uint16_t* qptr = Qp + (size_t)(b * NS + qbase + l15) * ND + h * NDK + g * 8;
    qf[0] = *(const bf16x8*)(qptr);
    qf[1] = *(const bf16x8*)(qptr + 32);
  }

  f32x4 acc[4] = {};
  float m_run[4] = {-INFINITY, -INFINITY, -INFINITY, -INFINITY};
  float l_run[4] = {0.f, 0.f, 0.f, 0.f};

  const int kr = t >> 2,  kc  = (t & 3) * 16;   // K staging: 4 thr/row, 16 cols
  const int vr = t & 63,  vdk = (t >> 6) * 16;  // V staging: 1 thr/row, 16 dk

  for(int kv0 = 0; kv0 < NS; kv0 += 64){
    { // stage K rows
      const uint16_t* src = Kp + (size_t)(b * NS + kv0 + kr) * ND + h * NDK + kc;
      *(bf16x8*)&Ksm[kr][kc]     = *(const bf16x8*)(src);
      *(bf16x8*)&Ksm[kr][kc + 8] = *(const bf16x8*)(src + 8);
    }
    { // stage V transposed: Vtsm[dk][kv]
      const uint16_t* src = Vp + (size_t)(b * NS + kv0 + vr) * ND + h * NDK + vdk;
      bf16x8 v0 = *(const bf16x8*)(src);
      bf16x8 v1 = *(const bf16x8*)(src + 8);
      #pragma unroll
      for(int j = 0; j < 8; ++j){
        Vtsm[vdk + j][vr]     = (uint16_t)(unsigned short)v0[j];
        Vtsm[vdk + 8 + j][vr] = (uint16_t)(unsigned short)v1[j];
      }
    }
    __syncthreads();

    #pragma unroll
    for(int c2 = 0; c2 < 2; ++c2){        // two 32-wide kv chunks
      f32x4 s[2];
      #pragma unroll
      for(int i = 0; i < 2; ++i){         // two 16-wide score tiles
        const int kvo = c2 * 32 + i * 16;
        bf16x8 kf0 = *(const bf16x8*)&Ksm[kvo + l15][g * 8];
        bf16x8 kf1 = *(const bf16x8*)&Ksm[kvo + l15][32 + g * 8];
        f32x4 zacc = {};
        zacc = MFMA_16x16x32_BF16(qf[0], kf0, zacc);
        zacc = MFMA_16x16x32_BF16(qf[1], kf1, zacc);
        // scale + mask (exactly like reference: masked -> -1e9 unscaled)
        const int kg = kv0 + kvo + l15;
        const int* mrow = mask + (size_t)(b * NS + q0 + w * 16 + g * 4) * NS + kg;
        #pragma unroll
        for(int j = 0; j < 4; ++j){
          int mv = mrow[(size_t)j * NS];
          zacc[j] = mv ? zacc[j] * 0.125f : -1e9f;
        }
        s[i] = zacc;
      }
      // row max over 32 cols (16-lane group butterfly)
      float tmax[4], fac[4], rs[4];
      #pragma unroll
      for(int j = 0; j < 4; ++j) tmax[j] = fmaxf(s[0][j], s[1][j]);
      #pragma unroll
      for(int off = 1; off <= 8; off <<= 1)
        #pragma unroll
        for(int j = 0; j < 4; ++j)
          tmax[j] = fmaxf(tmax[j], __shfl_xor(tmax[j], off, 64));
      #pragma unroll
      for(int j = 0; j < 4; ++j){
        float mn = fmaxf(m_run[j], tmax[j]);
        fac[j] = __expf(m_run[j] - mn);
        m_run[j] = mn;
      }
      #pragma unroll
      for(int i = 0; i < 2; ++i)
        #pragma unroll
        for(int j = 0; j < 4; ++j)
          s[i][j] = __expf(s[i][j] - m_run[j]);
      #pragma unroll
      for(int j = 0; j < 4; ++j) rs[j] = s[0][j] + s[1][j];
      #pragma unroll
      for(int off = 1; off <= 8; off <<= 1)
        #pragma unroll
        for(int j = 0; j < 4; ++j)
          rs[j] += __shfl_xor(rs[j], off, 64);
      #pragma unroll
      for(int j = 0; j < 4; ++j) l_run[j] = l_run[j] * fac[j] + rs[j];
      #pragma unroll
      for(int tt = 0; tt < 4; ++tt)
        #pragma unroll
        for(int j = 0; j < 4; ++j)
          acc[tt][j] *= fac[j];
      // P -> LDS (per-wave buffer), then read back in A-frag layout
      #pragma unroll
      for(int i = 0; i < 2; ++i)
        #pragma unroll
        for(int j = 0; j < 4; ++j)
          Psm[w][g * 4 + j][i * 16 + l15] = f2bf(s[i][j]);
      __syncthreads();
      bf16x8 pf = *(const bf16x8*)&Psm[w][l15][g * 8];
      #pragma unroll
      for(int tt = 0; tt < 4; ++tt){
        bf16x8 vf = *(const bf16x8*)&Vtsm[tt * 16 + l15][c2 * 32 + g * 8];
        acc[tt] = MFMA_16x16x32_BF16(pf, vf, acc[tt]);
      }
    }
    __syncthreads();   // staging buffers reused next kv tile
  }

  // finalize: divide by l, write X[b, q, h*64 + dk] as bf16
  #pragma unroll
  for(int tt = 0; tt < 4; ++tt){
    #pragma unroll
    for(int j = 0; j < 4; ++j){
      const int qr = qbase + g * 4 + j;
      float v = acc[tt][j] * (1.0f / l_run[j]);
      Xo[(size_t)(b * NS + qr) * ND + h * NDK + tt * 16 + l15] = f2bf(v);
    }
  }
}

// ---------------- host launch ------------------------------------------------
extern "C" void kernel_launch(void* const* d_in, const int* in_sizes, int n_in,
                              void* d_out, int out_size, void* d_ws, size_t ws_size,
                              hipStream_t stream)
{
  const float* query = (const float*)d_in[0];
  const float* key   = (const float*)d_in[1];
  const float* value = (const float*)d_in[2];
  const int*   mask  = (const int*)d_in[3];
  const float* Wq = (const float*)d_in[4];
  const float* bq = (const float*)d_in[5];
  const float* Wk = (const float*)d_in[6];
  const float* bk = (const float*)d_in[7];
  const float* Wv = (const float*)d_in[8];
  const float* bv = (const float*)d_in[9];
  const float* Wo = (const float*)d_in[10];
  const float* bo = (const float*)d_in[11];
  float* out = (float*)d_out;

  const size_t NX = (size_t)NB * NS * ND;   // 4,194,304
  const size_t NW = (size_t)ND * ND;        // 1,048,576

  uint16_t* ws  = (uint16_t*)d_ws;
  uint16_t* Xq  = ws;            // bf16 copies of activations
  uint16_t* Xk  = Xq  + NX;
  uint16_t* Xv  = Xk  + NX;
  uint16_t* Wqb = Xv  + NX;      // bf16 weights
  uint16_t* Wkb = Wqb + NW;
  uint16_t* Wvb = Wkb + NW;
  uint16_t* Wob = Wvb + NW;
  uint16_t* Qp  = Wob + NW;      // projected Q/K/V  [B,S,H*DK]
  uint16_t* Kp  = Qp  + NX;
  uint16_t* Vp  = Kp  + NX;
  uint16_t* Xa  = Vp  + NX;      // attention output [B,S,D]

  auto cvt = [&](const float* in, uint16_t* o, size_t n){
    int n8 = (int)(n / 8);
    int blocks = (n8 + 255) / 256; if (blocks > 2048) blocks = 2048;
    cvt_f32_bf16<<<blocks, 256, 0, stream>>>(in, o, n8);
  };
  cvt(query, Xq, NX); cvt(key, Xk, NX); cvt(value, Xv, NX);
  cvt(Wq, Wqb, NW);   cvt(Wk, Wkb, NW); cvt(Wv, Wvb, NW); cvt(Wo, Wob, NW);

  // fused QKV projections: grid (N/128, M/128, 3)
  dim3 gproj(ND / 128, (NB * NS) / 128, 3);
  gemm_bt<false><<<gproj, 256, 0, stream>>>(Xq, Xk, Xv,
                                            Wqb, Wkb, Wvb,
                                            bq, bk, bv,
                                            (void*)Qp, (void*)Kp, (void*)Vp,
                                            NB * NS, ND, ND);

  attn_fwd<<<dim3(NS / 64, NH, NB), 256, 0, stream>>>(Qp, Kp, Vp, mask, Xa);

  dim3 gout(ND / 128, (NB * NS) / 128, 1);
  gemm_bt<true><<<gout, 256, 0, stream>>>(Xa, Xa, Xa,
                                          Wob, Wob, Wob,
                                          bo, bo, bo,
                                          (void*)out, (void*)out, (void*)out,
                                          NB * NS, ND, ND);
}

// Round 2
// 240.245 us; speedup vs baseline: 1.1541x; 1.1541x over previous
//
#include <hip/hip_runtime.h>
#include <hip/hip_bf16.h>
#include <cstdint>
#include <cstddef>

#define NB 2
#define NS 2048
#define ND 1024
#define NH 16
#define NDK 64

typedef __attribute__((ext_vector_type(4))) float f32x4;
typedef __attribute__((ext_vector_type(8))) short bf16x8;

#define MFMA_16x16x32_BF16(a,b,c) __builtin_amdgcn_mfma_f32_16x16x32_bf16((a),(b),(c),0,0,0)

__device__ __forceinline__ uint16_t f2bf(float f){
  uint32_t u = __float_as_uint(f);
  u += 0x7fffu + ((u >> 16) & 1u);   // round-to-nearest-even
  return (uint16_t)(u >> 16);
}
__device__ __forceinline__ float bf2f(uint16_t u){
  return __uint_as_float(((uint32_t)u) << 16);
}

// ---------------- f32 -> bf16 convert (vectorized, 8 elem/thread/iter) ------
__global__ void cvt_f32_bf16(const float* __restrict__ in, uint16_t* __restrict__ out, int n8){
  int i0 = blockIdx.x * blockDim.x + threadIdx.x;
  int stride = gridDim.x * blockDim.x;
  for(int i = i0; i < n8; i += stride){
    const float4* p = (const float4*)(in) + (size_t)i * 2;
    float4 a = p[0], b = p[1];
    bf16x8 o;
    o[0]=(short)f2bf(a.x); o[1]=(short)f2bf(a.y); o[2]=(short)f2bf(a.z); o[3]=(short)f2bf(a.w);
    o[4]=(short)f2bf(b.x); o[5]=(short)f2bf(b.y); o[6]=(short)f2bf(b.z); o[7]=(short)f2bf(b.w);
    *((bf16x8*)(out) + i) = o;
  }
}

// ---------------- int32 mask -> bf16 additive bias (0 or -1e9) --------------
__global__ void mask_bias(const int* __restrict__ mask, uint16_t* __restrict__ bias, int n8){
  int i0 = blockIdx.x * blockDim.x + threadIdx.x;
  int stride = gridDim.x * blockDim.x;
  const short NEG = (short)0xCE6E;   // bf16(-1e9)
  for(int i = i0; i < n8; i += stride){
    const int4* p = (const int4*)(mask) + (size_t)i * 2;
    int4 a = p[0], b = p[1];
    bf16x8 o;
    o[0] = a.x ? 0 : NEG; o[1] = a.y ? 0 : NEG; o[2] = a.z ? 0 : NEG; o[3] = a.w ? 0 : NEG;
    o[4] = b.x ? 0 : NEG; o[5] = b.y ? 0 : NEG; o[6] = b.z ? 0 : NEG; o[7] = b.w ? 0 : NEG;
    *((bf16x8*)(bias) + i) = o;
  }
}

// ---------------- V [b,s,h*64+dk] -> Vt [(b,h),dk,s] ------------------------
__global__ __launch_bounds__(256)
void vtrans(const uint16_t* __restrict__ Vp, uint16_t* __restrict__ Vt){
  __shared__ __align__(16) uint16_t T[64][72];
  const int t = threadIdx.x;
  const int b = blockIdx.z, h = blockIdx.y, s0 = blockIdx.x * 64;
  const int r = t >> 2, c0 = (t & 3) * 16;
  const uint16_t* src = Vp + (size_t)(b * NS + s0 + r) * ND + h * NDK + c0;
  *(bf16x8*)&T[r][c0]     = *(const bf16x8*)(src);
  *(bf16x8*)&T[r][c0 + 8] = *(const bf16x8*)(src + 8);
  __syncthreads();
  bf16x8 o0, o1;
  #pragma unroll
  for(int e = 0; e < 8; ++e){ o0[e] = (short)T[c0 + e][r]; o1[e] = (short)T[c0 + 8 + e][r]; }
  uint16_t* dst = Vt + ((size_t)(b * NH + h) * NDK + r) * NS + s0 + c0;
  *(bf16x8*)dst       = o0;
  *(bf16x8*)(dst + 8) = o1;
}

// ---------------- GEMM: C[m,n] = sum_k A[m,k]*W[n,k] + bias[n] --------------
template<bool OUTF32>
__global__ __launch_bounds__(256)
void gemm_bt(const uint16_t* __restrict__ A0, const uint16_t* __restrict__ A1, const uint16_t* __restrict__ A2,
             const uint16_t* __restrict__ W0, const uint16_t* __restrict__ W1, const uint16_t* __restrict__ W2,
             const float* __restrict__ b0, const float* __restrict__ b1, const float* __restrict__ b2,
             void* __restrict__ C0, void* __restrict__ C1, void* __restrict__ C2,
             int M, int N, int K)
{
  const int z = blockIdx.z;
  const uint16_t* A   = (z == 0) ? A0 : (z == 1) ? A1 : A2;
  const uint16_t* W   = (z == 0) ? W0 : (z == 1) ? W1 : W2;
  const float*   bias = (z == 0) ? b0 : (z == 1) ? b1 : b2;
  void*          Cout = (z == 0) ? C0 : (z == 1) ? C1 : C2;

  __shared__ __align__(16) uint16_t Asm[128][40];
  __shared__ __align__(16) uint16_t Bsm[128][40];

  const int t = threadIdx.x;
  const int lane = t & 63, w = t >> 6;
  const int l15 = lane & 15, g = lane >> 4;
  const int bm = blockIdx.y * 128, bn = blockIdx.x * 128;
  const int wr = (w >> 1) * 64, wc = (w & 1) * 64;

  f32x4 acc[4][4] = {};

  const int sr = t >> 2, sc = (t & 3) * 8;

  for(int k0 = 0; k0 < K; k0 += 32){
    #pragma unroll
    for(int i = 0; i < 2; ++i){
      int r = sr + i * 64;
      *(bf16x8*)&Asm[r][sc] = *(const bf16x8*)(A + (size_t)(bm + r) * K + k0 + sc);
      *(bf16x8*)&Bsm[r][sc] = *(const bf16x8*)(W + (size_t)(bn + r) * K + k0 + sc);
    }
    __syncthreads();
    bf16x8 af[4], bfr[4];
    #pragma unroll
    for(int m = 0; m < 4; ++m) af[m]  = *(const bf16x8*)&Asm[wr + m*16 + l15][g*8];
    #pragma unroll
    for(int n = 0; n < 4; ++n) bfr[n] = *(const bf16x8*)&Bsm[wc + n*16 + l15][g*8];
    #pragma unroll
    for(int m = 0; m < 4; ++m)
      #pragma unroll
      for(int n = 0; n < 4; ++n)
        acc[m][n] = MFMA_16x16x32_BF16(af[m], bfr[n], acc[m][n]);
    __syncthreads();
  }

  #pragma unroll
  for(int m = 0; m < 4; ++m){
    const int row = bm + wr + m*16 + g*4;
    #pragma unroll
    for(int n = 0; n < 4; ++n){
      const int col = bn + wc + n*16 + l15;
      const float bv = bias[col];
      #pragma unroll
      for(int j = 0; j < 4; ++j){
        float v = acc[m][n][j] + bv;
        if (OUTF32) ((float*)Cout)[(size_t)(row + j) * N + col] = v;
        else        ((uint16_t*)Cout)[(size_t)(row + j) * N + col] = f2bf(v);
      }
    }
  }
}

// ---------------- Flash attention -------------------------------------------
// Grid (S/64, H, B), 256 threads = 4 waves, wave w owns 16 q-rows.
// K tile and Vt tile in XOR-chunk-swizzled LDS [64][64]; bias tile [64][72];
// per-wave P buffer swizzled. One softmax per 64-wide kv tile.
__device__ __forceinline__ int swz64(int r, int chunk){
  return r * 64 + (((chunk) ^ (r & 7)) << 3);
}

__global__ __launch_bounds__(256)
void attn_fwd(const uint16_t* __restrict__ Qp, const uint16_t* __restrict__ Kp,
              const uint16_t* __restrict__ Vtg, const uint16_t* __restrict__ BiasG,
              uint16_t* __restrict__ Xo)
{
  __shared__ __align__(16) uint16_t Ksm[64 * 64];
  __shared__ __align__(16) uint16_t Vtsm[64 * 64];
  __shared__ __align__(16) uint16_t Psm[4][16 * 64];
  __shared__ __align__(16) uint16_t Bsm[64][72];

  const int t = threadIdx.x, lane = t & 63, w = t >> 6;
  const int l15 = lane & 15, g = lane >> 4;
  const int b = blockIdx.z, h = blockIdx.y, q0 = blockIdx.x * 64;
  const int qbase = q0 + w * 16;

  bf16x8 qf0, qf1;
  {
    const uint16_t* qptr = Qp + (size_t)(b * NS + qbase + l15) * ND + h * NDK + g * 8;
    qf0 = *(const bf16x8*)(qptr);
    qf1 = *(const bf16x8*)(qptr + 32);
  }

  f32x4 acc[4] = {};
  float m_run[4] = {-INFINITY, -INFINITY, -INFINITY, -INFINITY};
  float l_run[4] = {0.f, 0.f, 0.f, 0.f};

  const int sr = t >> 2;          // staging row 0..63
  const int sc2 = (t & 3) * 2;    // staging chunk pair base (chunks of 8 elems)

  const uint16_t* Kbase = Kp + (size_t)(b * NS) * ND + h * NDK;
  const uint16_t* Vbase = Vtg + (size_t)(b * NH + h) * NDK * NS;
  const uint16_t* Mbase = BiasG + ((size_t)b * NS + q0) * NS;

  for(int kv0 = 0; kv0 < NS; kv0 += 64){
    { const uint16_t* s = Kbase + (size_t)(kv0 + sr) * ND + sc2 * 8;
      *(bf16x8*)&Ksm[swz64(sr, sc2)]     = *(const bf16x8*)(s);
      *(bf16x8*)&Ksm[swz64(sr, sc2 + 1)] = *(const bf16x8*)(s + 8); }
    { const uint16_t* s = Vbase + (size_t)sr * NS + kv0 + sc2 * 8;
      *(bf16x8*)&Vtsm[swz64(sr, sc2)]     = *(const bf16x8*)(s);
      *(bf16x8*)&Vtsm[swz64(sr, sc2 + 1)] = *(const bf16x8*)(s + 8); }
    { const uint16_t* s = Mbase + (size_t)sr * NS + kv0 + sc2 * 8;
      *(bf16x8*)&Bsm[sr][sc2 * 8]     = *(const bf16x8*)(s);
      *(bf16x8*)&Bsm[sr][sc2 * 8 + 8] = *(const bf16x8*)(s + 8); }
    __syncthreads();

    // QK^T over the full 64-wide tile
    f32x4 s4[4];
    #pragma unroll
    for(int i = 0; i < 4; ++i){
      bf16x8 kf0 = *(const bf16x8*)&Ksm[swz64(i * 16 + l15, g)];
      bf16x8 kf1 = *(const bf16x8*)&Ksm[swz64(i * 16 + l15, g + 4)];
      f32x4 z = {};
      z = MFMA_16x16x32_BF16(qf0, kf0, z);
      z = MFMA_16x16x32_BF16(qf1, kf1, z);
      s4[i] = z;
    }
    // scale + additive mask bias
    #pragma unroll
    for(int i = 0; i < 4; ++i)
      #pragma unroll
      for(int j = 0; j < 4; ++j)
        s4[i][j] = s4[i][j] * 0.125f + bf2f(Bsm[w * 16 + g * 4 + j][i * 16 + l15]);

    // online softmax over 64 cols: in-reg max over i, butterfly over 16-lane group
    float tmax[4], fac[4], rs[4];
    #pragma unroll
    for(int j = 0; j < 4; ++j)
      tmax[j] = fmaxf(fmaxf(s4[0][j], s4[1][j]), fmaxf(s4[2][j], s4[3][j]));
    #pragma unroll
    for(int off = 1; off <= 8; off <<= 1)
      #pragma unroll
      for(int j = 0; j < 4; ++j)
        tmax[j] = fmaxf(tmax[j], __shfl_xor(tmax[j], off, 64));
    #pragma unroll
    for(int j = 0; j < 4; ++j){
      float mn = fmaxf(m_run[j], tmax[j]);
      fac[j] = __expf(m_run[j] - mn);
      m_run[j] = mn;
    }
    #pragma unroll
    for(int i = 0; i < 4; ++i)
      #pragma unroll
      for(int j = 0; j < 4; ++j)
        s4[i][j] = __expf(s4[i][j] - m_run[j]);
    #pragma unroll
    for(int j = 0; j < 4; ++j)
      rs[j] = (s4[0][j] + s4[1][j]) + (s4[2][j] + s4[3][j]);
    #pragma unroll
    for(int off = 1; off <= 8; off <<= 1)
      #pragma unroll
      for(int j = 0; j < 4; ++j)
        rs[j] += __shfl_xor(rs[j], off, 64);
    #pragma unroll
    for(int j = 0; j < 4; ++j) l_run[j] = l_run[j] * fac[j] + rs[j];
    #pragma unroll
    for(int tt = 0; tt < 4; ++tt)
      #pragma unroll
      for(int j = 0; j < 4; ++j)
        acc[tt][j] *= fac[j];

    // P -> per-wave swizzled LDS (no block barrier needed)
    #pragma unroll
    for(int i = 0; i < 4; ++i){
      const int chunk = i * 2 + (l15 >> 3);
      #pragma unroll
      for(int j = 0; j < 4; ++j){
        const int r = g * 4 + j;
        Psm[w][r * 64 + (((chunk) ^ (r & 7)) << 3) + (l15 & 7)] = f2bf(s4[i][j]);
      }
    }
    #pragma unroll
    for(int c2 = 0; c2 < 2; ++c2){
      bf16x8 pf = *(const bf16x8*)&Psm[w][swz64(l15, c2 * 4 + g)];
      #pragma unroll
      for(int tt = 0; tt < 4; ++tt){
        bf16x8 vf = *(const bf16x8*)&Vtsm[swz64(tt * 16 + l15, c2 * 4 + g)];
        acc[tt] = MFMA_16x16x32_BF16(pf, vf, acc[tt]);
      }
    }
    __syncthreads();   // staging buffers reused next tile
  }

  #pragma unroll
  for(int j = 0; j < 4; ++j){
    const float inv = 1.0f / l_run[j];
    const int qr = qbase + g * 4 + j;
    #pragma unroll
    for(int tt = 0; tt < 4; ++tt)
      Xo[(size_t)(b * NS + qr) * ND + h * NDK + tt * 16 + l15] = f2bf(acc[tt][j] * inv);
  }
}

// ---------------- host launch ------------------------------------------------
extern "C" void kernel_launch(void* const* d_in, const int* in_sizes, int n_in,
                              void* d_out, int out_size, void* d_ws, size_t ws_size,
                              hipStream_t stream)
{
  const float* query = (const float*)d_in[0];
  const float* key   = (const float*)d_in[1];
  const float* value = (const float*)d_in[2];
  const int*   mask  = (const int*)d_in[3];
  const float* Wq = (const float*)d_in[4];
  const float* bq = (const float*)d_in[5];
  const float* Wk = (const float*)d_in[6];
  const float* bk = (const float*)d_in[7];
  const float* Wv = (const float*)d_in[8];
  const float* bv = (const float*)d_in[9];
  const float* Wo = (const float*)d_in[10];
  const float* bo = (const float*)d_in[11];
  float* out = (float*)d_out;

  const size_t NX = (size_t)NB * NS * ND;   // 4,194,304
  const size_t NW = (size_t)ND * ND;        // 1,048,576

  uint16_t* ws  = (uint16_t*)d_ws;
  uint16_t* Xq  = ws;            // bf16 activations; after proj: bias lives in Xq..Xk
  uint16_t* Xk  = Xq  + NX;
  uint16_t* Xv  = Xk  + NX;      // after proj: Vt lives here
  uint16_t* Wqb = Xv  + NX;
  uint16_t* Wkb = Wqb + NW;
  uint16_t* Wvb = Wkb + NW;
  uint16_t* Wob = Wvb + NW;
  uint16_t* Qp  = Wob + NW;
  uint16_t* Kp  = Qp  + NX;
  uint16_t* Vp  = Kp  + NX;
  uint16_t* Xa  = Vp  + NX;

  uint16_t* BiasB = Xq;          // B*S*S bf16 = 2*NX elems (Xq+Xk region)
  uint16_t* Vt    = Xv;          // B*H*DK*S = NX elems

  auto cvt = [&](const float* in, uint16_t* o, size_t n){
    int n8 = (int)(n / 8);
    int blocks = (n8 + 255) / 256; if (blocks > 2048) blocks = 2048;
    cvt_f32_bf16<<<blocks, 256, 0, stream>>>(in, o, n8);
  };
  cvt(query, Xq, NX); cvt(key, Xk, NX); cvt(value, Xv, NX);
  cvt(Wq, Wqb, NW);   cvt(Wk, Wkb, NW); cvt(Wv, Wvb, NW); cvt(Wo, Wob, NW);

  dim3 gproj(ND / 128, (NB * NS) / 128, 3);
  gemm_bt<false><<<gproj, 256, 0, stream>>>(Xq, Xk, Xv,
                                            Wqb, Wkb, Wvb,
                                            bq, bk, bv,
                                            (void*)Qp, (void*)Kp, (void*)Vp,
                                            NB * NS, ND, ND);

  // after proj: activations dead -> build bias + Vt in their place
  {
    int n8 = (int)((size_t)NB * NS * NS / 8);
    int blocks = (n8 + 255) / 256; if (blocks > 2048) blocks = 2048;
    mask_bias<<<blocks, 256, 0, stream>>>(mask, BiasB, n8);
  }
  vtrans<<<dim3(NS / 64, NH, NB), 256, 0, stream>>>(Vp, Vt);

  attn_fwd<<<dim3(NS / 64, NH, NB), 256, 0, stream>>>(Qp, Kp, Vt, BiasB, Xa);

  dim3 gout(ND / 128, (NB * NS) / 128, 1);
  gemm_bt<true><<<gout, 256, 0, stream>>>(Xa, Xa, Xa,
                                          Wob, Wob, Wob,
                                          bo, bo, bo,
                                          (void*)out, (void*)out, (void*)out,
                                          NB * NS, ND, ND);
}

// Round 3
// 188.344 us; speedup vs baseline: 1.4721x; 1.2756x over previous
//
#include <hip/hip_runtime.h>
#include <hip/hip_bf16.h>
#include <cstdint>
#include <cstddef>

#define NB 2
#define NS 2048
#define ND 1024
#define NH 16
#define NDK 64

typedef __attribute__((ext_vector_type(4))) float f32x4;
typedef __attribute__((ext_vector_type(8))) short bf16x8;

#define MFMA_16x16x32_BF16(a,b,c) __builtin_amdgcn_mfma_f32_16x16x32_bf16((a),(b),(c),0,0,0)

__device__ __forceinline__ uint16_t f2bf(float f){
  uint32_t u = __float_as_uint(f);
  u += 0x7fffu + ((u >> 16) & 1u);   // round-to-nearest-even
  return (uint16_t)(u >> 16);
}
__device__ __forceinline__ float bf2f(uint16_t u){
  return __uint_as_float(((uint32_t)u) << 16);
}
// packed f32x2 -> bf16x2 (RNE) in one HW instruction (T12 recipe)
__device__ __forceinline__ uint32_t bfpack2(float a, float b){
  uint32_t r;
  asm volatile("v_cvt_pk_bf16_f32 %0, %1, %2" : "=v"(r) : "v"(a), "v"(b));
  return r;
}
// async global->LDS, 16B per lane; LDS dest = wave-uniform base + lane*16
__device__ __forceinline__ void gload_lds16(const void* g, void* l){
  __builtin_amdgcn_global_load_lds((const __attribute__((address_space(1))) void*)g,
                                   (__attribute__((address_space(3))) void*)l, 16, 0, 0);
}

// ---------------- f32 -> bf16 convert ---------------------------------------
__global__ void cvt_f32_bf16(const float* __restrict__ in, uint16_t* __restrict__ out, int n8){
  int i0 = blockIdx.x * blockDim.x + threadIdx.x;
  int stride = gridDim.x * blockDim.x;
  for(int i = i0; i < n8; i += stride){
    const float4* p = (const float4*)(in) + (size_t)i * 2;
    float4 a = p[0], b = p[1];
    bf16x8 o;
    o[0]=(short)f2bf(a.x); o[1]=(short)f2bf(a.y); o[2]=(short)f2bf(a.z); o[3]=(short)f2bf(a.w);
    o[4]=(short)f2bf(b.x); o[5]=(short)f2bf(b.y); o[6]=(short)f2bf(b.z); o[7]=(short)f2bf(b.w);
    *((bf16x8*)(out) + i) = o;
  }
}

// ---------------- int32 mask -> bf16 additive bias (0 or -1e9) --------------
__global__ void mask_bias(const int* __restrict__ mask, uint16_t* __restrict__ bias, int n8){
  int i0 = blockIdx.x * blockDim.x + threadIdx.x;
  int stride = gridDim.x * blockDim.x;
  const short NEG = (short)0xCE6E;   // bf16(-1e9)
  for(int i = i0; i < n8; i += stride){
    const int4* p = (const int4*)(mask) + (size_t)i * 2;
    int4 a = p[0], b = p[1];
    bf16x8 o;
    o[0] = a.x ? 0 : NEG; o[1] = a.y ? 0 : NEG; o[2] = a.z ? 0 : NEG; o[3] = a.w ? 0 : NEG;
    o[4] = b.x ? 0 : NEG; o[5] = b.y ? 0 : NEG; o[6] = b.z ? 0 : NEG; o[7] = b.w ? 0 : NEG;
    *((bf16x8*)(bias) + i) = o;
  }
}

// ---------------- V [b,s,h*64+dk] -> Vt [(b,h),dk,s] ------------------------
__global__ __launch_bounds__(256)
void vtrans(const uint16_t* __restrict__ Vp, uint16_t* __restrict__ Vt){
  __shared__ __align__(16) uint16_t T[64][72];
  const int t = threadIdx.x;
  const int b = blockIdx.z, h = blockIdx.y, s0 = blockIdx.x * 64;
  const int r = t >> 2, c0 = (t & 3) * 16;
  const uint16_t* src = Vp + (size_t)(b * NS + s0 + r) * ND + h * NDK + c0;
  *(bf16x8*)&T[r][c0]     = *(const bf16x8*)(src);
  *(bf16x8*)&T[r][c0 + 8] = *(const bf16x8*)(src + 8);
  __syncthreads();
  bf16x8 o0, o1;
  #pragma unroll
  for(int e = 0; e < 8; ++e){ o0[e] = (short)T[c0 + e][r]; o1[e] = (short)T[c0 + 8 + e][r]; }
  uint16_t* dst = Vt + ((size_t)(b * NH + h) * NDK + r) * NS + s0 + c0;
  *(bf16x8*)dst       = o0;
  *(bf16x8*)(dst + 8) = o1;
}

// ---------------- GEMM: C[m,n] = sum_k A[m,k]*W[n,k] + bias[n] --------------
// 128x128 tile, BK=32, global_load_lds(16B) staging into linear [128][32] LDS.
template<bool OUTF32>
__global__ __launch_bounds__(256)
void gemm_bt(const uint16_t* __restrict__ A0, const uint16_t* __restrict__ A1, const uint16_t* __restrict__ A2,
             const uint16_t* __restrict__ W0, const uint16_t* __restrict__ W1, const uint16_t* __restrict__ W2,
             const float* __restrict__ b0, const float* __restrict__ b1, const float* __restrict__ b2,
             void* __restrict__ C0, void* __restrict__ C1, void* __restrict__ C2,
             int M, int N, int K)
{
  const int z = blockIdx.z;
  const uint16_t* A   = (z == 0) ? A0 : (z == 1) ? A1 : A2;
  const uint16_t* W   = (z == 0) ? W0 : (z == 1) ? W1 : W2;
  const float*   bias = (z == 0) ? b0 : (z == 1) ? b1 : b2;
  void*          Cout = (z == 0) ? C0 : (z == 1) ? C1 : C2;

  __shared__ __align__(16) uint16_t Asm[128 * 32];
  __shared__ __align__(16) uint16_t Bsm[128 * 32];

  const int t = threadIdx.x;
  const int lane = t & 63, w = t >> 6;
  const int l15 = lane & 15, g = lane >> 4;
  const int bm = blockIdx.y * 128, bn = blockIdx.x * 128;
  const int wr = (w >> 1) * 64, wc = (w & 1) * 64;

  f32x4 acc[4][4] = {};

  // staging geometry: wave w covers rows w*32..w*32+31 in two 16-row DMA calls
  const int srow = lane >> 2;          // 0..15 (4 lanes per 64B row)
  const int scol = (lane & 3) * 8;     // 0,8,16,24

  const uint16_t* gA = A + (size_t)(bm + w * 32 + srow) * K + scol;
  const uint16_t* gB = W + (size_t)(bn + w * 32 + srow) * K + scol;
  uint16_t* lA0 = &Asm[(w * 32) * 32];
  uint16_t* lA1 = &Asm[(w * 32 + 16) * 32];
  uint16_t* lB0 = &Bsm[(w * 32) * 32];
  uint16_t* lB1 = &Bsm[(w * 32 + 16) * 32];

  for(int k0 = 0; k0 < K; k0 += 32){
    gload_lds16(gA + k0,          lA0);
    gload_lds16(gA + k0 + 16 * K, lA1);
    gload_lds16(gB + k0,          lB0);
    gload_lds16(gB + k0 + 16 * K, lB1);
    __syncthreads();
    bf16x8 af[4], bfr[4];
    #pragma unroll
    for(int m = 0; m < 4; ++m) af[m]  = *(const bf16x8*)&Asm[(wr + m*16 + l15) * 32 + g * 8];
    #pragma unroll
    for(int n = 0; n < 4; ++n) bfr[n] = *(const bf16x8*)&Bsm[(wc + n*16 + l15) * 32 + g * 8];
    #pragma unroll
    for(int m = 0; m < 4; ++m)
      #pragma unroll
      for(int n = 0; n < 4; ++n)
        acc[m][n] = MFMA_16x16x32_BF16(af[m], bfr[n], acc[m][n]);
    __syncthreads();
  }

  #pragma unroll
  for(int m = 0; m < 4; ++m){
    const int row = bm + wr + m*16 + g*4;
    #pragma unroll
    for(int n = 0; n < 4; ++n){
      const int col = bn + wc + n*16 + l15;
      const float bv = bias[col];
      #pragma unroll
      for(int j = 0; j < 4; ++j){
        float v = acc[m][n][j] + bv;
        if (OUTF32) ((float*)Cout)[(size_t)(row + j) * N + col] = v;
        else        ((uint16_t*)Cout)[(size_t)(row + j) * N + col] = f2bf(v);
      }
    }
  }
}

// ---------------- Flash attention (swapped QK^T, in-lane softmax) -----------
// Grid (S/64, H, B), 256 threads = 4 waves, wave w owns 16 q-rows.
// QK^T computed as mfma(K,Q): score tile col=q(l15), row=kv(16i+g*4+j) ->
// softmax row is lane-local (16 scores/lane) + 2 cross-g shuffles.
__device__ __forceinline__ int swz64(int r, int chunk){
  return r * 64 + (((chunk) ^ (r & 7)) << 3);
}

__global__ __launch_bounds__(256)
void attn_fwd(const uint16_t* __restrict__ Qp, const uint16_t* __restrict__ Kp,
              const uint16_t* __restrict__ Vtg, const uint16_t* __restrict__ BiasG,
              uint16_t* __restrict__ Xo)
{
  __shared__ __align__(16) uint16_t Ksm[64 * 64];
  __shared__ __align__(16) uint16_t Vtsm[64 * 64];
  __shared__ __align__(16) uint16_t Bsm[64 * 64];
  __shared__ __align__(16) uint16_t Psm[4][16 * 64];

  const int t = threadIdx.x, lane = t & 63, w = t >> 6;
  const int l15 = lane & 15, g = lane >> 4;
  const int b = blockIdx.z, h = blockIdx.y, q0 = blockIdx.x * 64;
  const int qbase = q0 + w * 16;

  // Q fragment (B operand): row=l15=q, k-slice g*8 (+32)
  bf16x8 qf0, qf1;
  {
    const uint16_t* qptr = Qp + (size_t)(b * NS + qbase + l15) * ND + h * NDK + g * 8;
    qf0 = *(const bf16x8*)(qptr);
    qf1 = *(const bf16x8*)(qptr + 32);
  }

  f32x4 acc[4] = {};
  float m_run = -INFINITY;   // running max for q = l15 (replicated over g)
  float l_run = 0.f;         // running denom for q = l15

  const int sr = t >> 2;          // staging row 0..63
  const int sc2 = (t & 3) * 2;    // staging chunk pair (8-elem chunks)

  const uint16_t* Kbase = Kp + (size_t)(b * NS) * ND + h * NDK;
  const uint16_t* Vbase = Vtg + (size_t)(b * NH + h) * NDK * NS;
  const uint16_t* Mbase = BiasG + ((size_t)b * NS + q0) * NS;

  const int xorw = (l15 & 7) << 3;         // P/B row-XOR for this lane's q row
  const int prow = l15 * 64;

  for(int kv0 = 0; kv0 < NS; kv0 += 64){
    { const uint16_t* s = Kbase + (size_t)(kv0 + sr) * ND + sc2 * 8;
      *(bf16x8*)&Ksm[swz64(sr, sc2)]     = *(const bf16x8*)(s);
      *(bf16x8*)&Ksm[swz64(sr, sc2 + 1)] = *(const bf16x8*)(s + 8); }
    { const uint16_t* s = Vbase + (size_t)sr * NS + kv0 + sc2 * 8;
      *(bf16x8*)&Vtsm[swz64(sr, sc2)]     = *(const bf16x8*)(s);
      *(bf16x8*)&Vtsm[swz64(sr, sc2 + 1)] = *(const bf16x8*)(s + 8); }
    { const uint16_t* s = Mbase + (size_t)sr * NS + kv0 + sc2 * 8;
      *(bf16x8*)&Bsm[swz64(sr, sc2)]     = *(const bf16x8*)(s);
      *(bf16x8*)&Bsm[swz64(sr, sc2 + 1)] = *(const bf16x8*)(s + 8); }
    __syncthreads();

    // QK^T swapped: s4[i] row=kv(16i+g*4+j), col=q(l15)
    f32x4 s4[4];
    #pragma unroll
    for(int i = 0; i < 4; ++i){
      bf16x8 kf0 = *(const bf16x8*)&Ksm[swz64(i * 16 + l15, g)];
      bf16x8 kf1 = *(const bf16x8*)&Ksm[swz64(i * 16 + l15, g + 4)];
      f32x4 z = {};
      z = MFMA_16x16x32_BF16(kf0, qf0, z);
      z = MFMA_16x16x32_BF16(kf1, qf1, z);
      s4[i] = z;
    }

    // scale + additive bias: bias[q=w*16+l15][kv=16i+g*4 .. +3], b64 reads
    #pragma unroll
    for(int i = 0; i < 4; ++i){
      const int col = (16 * i + g * 4) ^ xorw;
      uint2 bb = *(const uint2*)&Bsm[(w * 16 + l15) * 64 + col];
      s4[i][0] = s4[i][0] * 0.125f + bf2f((uint16_t)(bb.x & 0xffff));
      s4[i][1] = s4[i][1] * 0.125f + bf2f((uint16_t)(bb.x >> 16));
      s4[i][2] = s4[i][2] * 0.125f + bf2f((uint16_t)(bb.y & 0xffff));
      s4[i][3] = s4[i][3] * 0.125f + bf2f((uint16_t)(bb.y >> 16));
    }

    // lane-local row max (16 values) + cross-g butterfly (2 shuffles)
    float tmax;
    {
      float a = fmaxf(fmaxf(s4[0][0], s4[0][1]), fmaxf(s4[0][2], s4[0][3]));
      float c = fmaxf(fmaxf(s4[1][0], s4[1][1]), fmaxf(s4[1][2], s4[1][3]));
      float d = fmaxf(fmaxf(s4[2][0], s4[2][1]), fmaxf(s4[2][2], s4[2][3]));
      float e = fmaxf(fmaxf(s4[3][0], s4[3][1]), fmaxf(s4[3][2], s4[3][3]));
      tmax = fmaxf(fmaxf(a, c), fmaxf(d, e));
    }
    tmax = fmaxf(tmax, __shfl_xor(tmax, 16, 64));
    tmax = fmaxf(tmax, __shfl_xor(tmax, 32, 64));

    // defer-max (T13): only rescale when some row's max grew past threshold
    if(__any(tmax > m_run + 8.0f)){
      float m_new = fmaxf(m_run, tmax);
      float fac = __expf(m_run - m_new);
      m_run = m_new;
      l_run *= fac;
      #pragma unroll
      for(int j = 0; j < 4; ++j){
        int src = (lane & 48) | (((lane >> 4) & 3) * 4 + j);
        float fj = __shfl(fac, src, 64);
        acc[0][j] *= fj; acc[1][j] *= fj; acc[2][j] *= fj; acc[3][j] *= fj;
      }
    }

    // p = exp(s - m), lane-local
    #pragma unroll
    for(int i = 0; i < 4; ++i)
      #pragma unroll
      for(int j = 0; j < 4; ++j)
        s4[i][j] = __expf(s4[i][j] - m_run);

    // row sum
    {
      float rs = ((s4[0][0] + s4[0][1]) + (s4[0][2] + s4[0][3]))
               + ((s4[1][0] + s4[1][1]) + (s4[1][2] + s4[1][3]))
               + ((s4[2][0] + s4[2][1]) + (s4[2][2] + s4[2][3]))
               + ((s4[3][0] + s4[3][1]) + (s4[3][2] + s4[3][3]));
      rs += __shfl_xor(rs, 16, 64);
      rs += __shfl_xor(rs, 32, 64);
      l_run += rs;
    }

    // pack P -> per-wave LDS: row q=l15, 4 adjacent kv per b64 write
    #pragma unroll
    for(int i = 0; i < 4; ++i){
      uint2 pk;
      pk.x = bfpack2(s4[i][0], s4[i][1]);
      pk.y = bfpack2(s4[i][2], s4[i][3]);
      const int col = (16 * i + g * 4) ^ xorw;
      *(uint2*)&Psm[w][prow + col] = pk;
    }

    // PV: pf A-frag row=q(l15), k=kv slice; vf B-frag row=dk(l15)
    #pragma unroll
    for(int c2 = 0; c2 < 2; ++c2){
      bf16x8 pf = *(const bf16x8*)&Psm[w][prow + ((c2 * 32 + g * 8) ^ xorw)];
      #pragma unroll
      for(int tt = 0; tt < 4; ++tt){
        bf16x8 vf = *(const bf16x8*)&Vtsm[swz64(tt * 16 + l15, c2 * 4 + g)];
        acc[tt] = MFMA_16x16x32_BF16(pf, vf, acc[tt]);
      }
    }
    __syncthreads();   // staging buffers reused next tile
  }

  // finalize: redistribute 1/l to output rows, write bf16
  #pragma unroll
  for(int j = 0; j < 4; ++j){
    int src = (lane & 48) | (((lane >> 4) & 3) * 4 + j);
    float lr = __shfl(l_run, src, 64);
    float inv = 1.0f / lr;
    const int qr = qbase + g * 4 + j;
    #pragma unroll
    for(int tt = 0; tt < 4; ++tt)
      Xo[(size_t)(b * NS + qr) * ND + h * NDK + tt * 16 + l15] = f2bf(acc[tt][j] * inv);
  }
}

// ---------------- host launch ------------------------------------------------
extern "C" void kernel_launch(void* const* d_in, const int* in_sizes, int n_in,
                              void* d_out, int out_size, void* d_ws, size_t ws_size,
                              hipStream_t stream)
{
  const float* query = (const float*)d_in[0];
  const float* key   = (const float*)d_in[1];
  const float* value = (const float*)d_in[2];
  const int*   mask  = (const int*)d_in[3];
  const float* Wq = (const float*)d_in[4];
  const float* bq = (const float*)d_in[5];
  const float* Wk = (const float*)d_in[6];
  const float* bk = (const float*)d_in[7];
  const float* Wv = (const float*)d_in[8];
  const float* bv = (const float*)d_in[9];
  const float* Wo = (const float*)d_in[10];
  const float* bo = (const float*)d_in[11];
  float* out = (float*)d_out;

  const size_t NX = (size_t)NB * NS * ND;   // 4,194,304
  const size_t NW = (size_t)ND * ND;        // 1,048,576

  uint16_t* ws  = (uint16_t*)d_ws;
  uint16_t* Xq  = ws;            // bf16 activations; after proj: bias lives here
  uint16_t* Xk  = Xq  + NX;
  uint16_t* Xv  = Xk  + NX;      // after proj: Vt lives here
  uint16_t* Wqb = Xv  + NX;
  uint16_t* Wkb = Wqb + NW;
  uint16_t* Wvb = Wkb + NW;
  uint16_t* Wob = Wvb + NW;
  uint16_t* Qp  = Wob + NW;
  uint16_t* Kp  = Qp  + NX;
  uint16_t* Vp  = Kp  + NX;
  uint16_t* Xa  = Vp  + NX;

  uint16_t* BiasB = Xq;          // B*S*S bf16 = 2*NX elems (Xq+Xk region)
  uint16_t* Vt    = Xv;          // B*H*DK*S = NX elems

  auto cvt = [&](const float* in, uint16_t* o, size_t n){
    int n8 = (int)(n / 8);
    int blocks = (n8 + 255) / 256; if (blocks > 2048) blocks = 2048;
    cvt_f32_bf16<<<blocks, 256, 0, stream>>>(in, o, n8);
  };
  cvt(query, Xq, NX); cvt(key, Xk, NX); cvt(value, Xv, NX);
  cvt(Wq, Wqb, NW);   cvt(Wk, Wkb, NW); cvt(Wv, Wvb, NW); cvt(Wo, Wob, NW);

  dim3 gproj(ND / 128, (NB * NS) / 128, 3);
  gemm_bt<false><<<gproj, 256, 0, stream>>>(Xq, Xk, Xv,
                                            Wqb, Wkb, Wvb,
                                            bq, bk, bv,
                                            (void*)Qp, (void*)Kp, (void*)Vp,
                                            NB * NS, ND, ND);

  // after proj: activations dead -> build bias + Vt in their place
  {
    int n8 = (int)((size_t)NB * NS * NS / 8);
    int blocks = (n8 + 255) / 256; if (blocks > 2048) blocks = 2048;
    mask_bias<<<blocks, 256, 0, stream>>>(mask, BiasB, n8);
  }
  vtrans<<<dim3(NS / 64, NH, NB), 256, 0, stream>>>(Vp, Vt);

  attn_fwd<<<dim3(NS / 64, NH, NB), 256, 0, stream>>>(Qp, Kp, Vt, BiasB, Xa);

  dim3 gout(ND / 128, (NB * NS) / 128, 1);
  gemm_bt<true><<<gout, 256, 0, stream>>>(Xa, Xa, Xa,
                                          Wob, Wob, Wob,
                                          bo, bo, bo,
                                          (void*)out, (void*)out, (void*)out,
                                          NB * NS, ND, ND);
}